// Round 4
// baseline (611.804 us; speedup 1.0000x reference)
//
#include <hip/hip_runtime.h>
#include <stdint.h>

// RPNHead fused: 3x3 conv(256->512,SAME)+relu6 -> {1x1 conv->30 + softmax-pairs, 1x1 conv->60}
// B=8 H=128 W=128. One block per (b,h) row: M=128 pos, N=512 ch, K=2304.
// R4: m201-style phase pipeline. 72 chunks x 2 phases; 16KB half-chunks staged into 4
// rotating LDS slots, issue distance 3, counted vmcnt(4) (never 0 in steady state).
// Per phase: ds_read frags -> issue half -> vmcnt(4) -> barrier -> lgkmcnt(0) -> 16 MFMA -> barrier.

#define HH 128
#define WW 128
#define CIN 256

typedef __attribute__((ext_vector_type(8))) short short8;
typedef __attribute__((ext_vector_type(4))) float f32x4;

#define LDS_B_OFF 66560            // A: [130 pos][256 ch] bf16 swizzled = 66560 B
#define LDS_TOTAL 132096           // + 4 x 16384 B half-chunk slots

static __device__ __forceinline__ unsigned short f2bf(float f) {
    uint32_t u = __float_as_uint(f);
    uint32_t r = (u + 0x7FFFu + ((u >> 16) & 1u)) >> 16;
    return (unsigned short)r;
}

// w_shared [3][3][256][512] f32 -> wk [72 chunks][512 n'][32 kk] bf16 (chunk c: dydx=c/8, kc=c%8)
// n' reorder: n = wn*128 + nf*16 + l  ->  n' = (nf>=4)<<8 | wn<<6 | (nf&3)<<4 | l
// so each phase's rows (nf 0-3 / 4-7 across all wn) form one contiguous 16KB half.
// kk pre-swizzled: kk ^ (((n'>>1)&3)<<3)  (both-sides swizzle; linear global_load_lds).
__global__ __launch_bounds__(256) void prep_wk(const float* __restrict__ w,
                                               unsigned short* __restrict__ wk) {
    __shared__ unsigned short t[32][130];
    const int c = blockIdx.x >> 2, nh = blockIdx.x & 3;   // nh = wn group (n>>7)
    const int dydx = c >> 3, kc = c & 7;
    #pragma unroll
    for (int e = 0; e < 16; ++e) {
        int idx = e * 256 + threadIdx.x;          // 32 kk x 128 n
        int kk = idx >> 7, n0 = idx & 127;
        float v = w[((size_t)(dydx * 256 + kc * 32 + kk)) * 512 + nh * 128 + n0];
        t[kk][n0] = f2bf(v);
    }
    __syncthreads();
    #pragma unroll
    for (int e = 0; e < 16; ++e) {
        int idx = e * 256 + threadIdx.x;          // 128 n0 x 32 kk
        int n0 = idx >> 5, kk = idx & 31;
        int nf = n0 >> 4, l = n0 & 15;
        int np = ((nf >> 2) << 8) | (nh << 6) | ((nf & 3) << 4) | l;
        int kks = kk ^ (((np >> 1) & 3) << 3);
        wk[(size_t)c * 16384 + (size_t)np * 32 + kks] = t[kk][n0];
    }
}

// w_cls [512][30], w_reg [512][60] -> wbr [96 n][512 k] bf16 (n 0..29=cls, 32..91=reg, rest 0)
__global__ __launch_bounds__(256) void prep_wbr(const float* __restrict__ wc,
                                                const float* __restrict__ wr,
                                                unsigned short* __restrict__ wbr) {
    int t = blockIdx.x * 256 + threadIdx.x;       // 49,152 total
    int n = t >> 9, k = t & 511;
    float v = 0.f;
    if (n < 30) v = wc[k * 30 + n];
    else if (n >= 32 && n < 92) v = wr[k * 60 + (n - 32)];
    wbr[n * 512 + k] = f2bf(v);
}

__global__ __launch_bounds__(512, 2) void rpn_fused(
    const float* __restrict__ x, const unsigned short* __restrict__ wk,
    const float* __restrict__ bsh, const unsigned short* __restrict__ wbr,
    const float* __restrict__ bcls, const float* __restrict__ breg,
    float* __restrict__ out)
{
    extern __shared__ char smem[];
    const int tid = threadIdx.x;
    const int lane = tid & 63;
    const int wid = tid >> 6;            // 0..7
    const int wm = wid >> 2, wn = wid & 3;
    const int l15 = lane & 15, l4 = lane >> 4;
    const int blk = blockIdx.x;
    const int bb = blk >> 7, h = blk & 127;

    // per-lane constant B byte offset within a 16KB half-slot (nf adds nf*1024):
    const int bofs = (wn * 64 + l15) * 64 + ((l4 * 16) ^ (((l15 >> 1) & 3) << 4));

    f32x4 acc[4][8];
    #pragma unroll
    for (int i = 0; i < 4; ++i)
        #pragma unroll
        for (int j = 0; j < 8; ++j) acc[i][j] = (f32x4){0.f, 0.f, 0.f, 0.f};

#define ISSUE_HALF(hh)                                                            \
    if ((hh) < 144) {                                                             \
        const char* s_ = reinterpret_cast<const char*>(wk) + ((size_t)(hh) << 14) \
                         + tid * 16;                                              \
        char* d_ = smem + LDS_B_OFF + (((hh) & 3) << 14) + tid * 16;              \
        __builtin_amdgcn_global_load_lds(reinterpret_cast<const uint32_t*>(s_),   \
                                         reinterpret_cast<uint32_t*>(d_), 16, 0, 0); \
        __builtin_amdgcn_global_load_lds(reinterpret_cast<const uint32_t*>(s_ + 8192), \
                                         reinterpret_cast<uint32_t*>(d_ + 8192), 16, 0, 0); \
    }

#define WAITV(tt)                                                          \
    if ((tt) <= 140)      asm volatile("s_waitcnt vmcnt(4)" ::: "memory"); \
    else if ((tt) == 141) asm volatile("s_waitcnt vmcnt(2)" ::: "memory"); \
    else                  asm volatile("s_waitcnt vmcnt(0)" ::: "memory");

    // ---- prologue: issue halves 0..2
    ISSUE_HALF(0); ISSUE_HALF(1); ISSUE_HALF(2);

    for (int dy = 0; dy < 3; ++dy) {
        // ---- A stage: one input row hp -> LDS [130 pos][256 ch] bf16, swizzled
        {
            const int hp = h + dy - 1;
            const bool hin = (hp >= 0) && (hp < HH);
            const float* xrow = x + ((size_t)(bb * HH + hp)) * WW * CIN;
            for (int u = tid; u < 130 * 32; u += 512) {
                const int pos = u >> 5, c8 = u & 31;
                const int wc = pos - 1;
                float4 f0 = make_float4(0.f,0.f,0.f,0.f), f1 = make_float4(0.f,0.f,0.f,0.f);
                if (hin && (unsigned)wc < WW) {
                    const float4* p = reinterpret_cast<const float4*>(xrow + (size_t)wc * CIN + c8 * 8);
                    f0 = p[0]; f1 = p[1];
                }
                short8 v;
                v[0]=(short)f2bf(f0.x); v[1]=(short)f2bf(f0.y);
                v[2]=(short)f2bf(f0.z); v[3]=(short)f2bf(f0.w);
                v[4]=(short)f2bf(f1.x); v[5]=(short)f2bf(f1.y);
                v[6]=(short)f2bf(f1.z); v[7]=(short)f2bf(f1.w);
                *reinterpret_cast<short8*>(smem + pos * 512 + ((c8 * 16) ^ ((pos & 7) << 4))) = v;
            }
        }
        if (dy == 0) asm volatile("s_waitcnt vmcnt(4) lgkmcnt(0)" ::: "memory");  // half0 landed
        else         asm volatile("s_waitcnt lgkmcnt(0)" ::: "memory");           // keep prefetch alive
        __builtin_amdgcn_sched_barrier(0);
        __builtin_amdgcn_s_barrier();      // A visible to all; (dy0) half0..2 staged

        for (int i = 0; i < 24; ++i) {
            const int g = dy * 24 + i;
            const int t0 = 2 * g;
            const int dx = i >> 3, kc = i & 7;

            // ================= phase 0: A frags + B nf0-3, MFMA quadrant nf0-3
            const char* slot0 = smem + LDS_B_OFF + ((t0 & 3) << 14);
            const int r0 = wm * 64 + l15 + dx;
            const int asw = ((kc * 32 + l4 * 8) << 1) ^ ((r0 & 7) << 4);
            short8 af0 = *reinterpret_cast<const short8*>(smem + (r0     ) * 512 + asw);
            short8 af1 = *reinterpret_cast<const short8*>(smem + (r0 + 16) * 512 + asw);
            short8 af2 = *reinterpret_cast<const short8*>(smem + (r0 + 32) * 512 + asw);
            short8 af3 = *reinterpret_cast<const short8*>(smem + (r0 + 48) * 512 + asw);
            short8 b0 = *reinterpret_cast<const short8*>(slot0 + bofs);
            short8 b1 = *reinterpret_cast<const short8*>(slot0 + bofs + 1024);
            short8 b2 = *reinterpret_cast<const short8*>(slot0 + bofs + 2048);
            short8 b3 = *reinterpret_cast<const short8*>(slot0 + bofs + 3072);
            ISSUE_HALF(t0 + 3);
            WAITV(t0);
            __builtin_amdgcn_s_barrier();
            asm volatile("s_waitcnt lgkmcnt(0)" ::: "memory");
            __builtin_amdgcn_sched_barrier(0);
            __builtin_amdgcn_s_setprio(1);
            acc[0][0] = __builtin_amdgcn_mfma_f32_16x16x32_bf16(af0, b0, acc[0][0], 0, 0, 0);
            acc[1][0] = __builtin_amdgcn_mfma_f32_16x16x32_bf16(af1, b0, acc[1][0], 0, 0, 0);
            acc[2][0] = __builtin_amdgcn_mfma_f32_16x16x32_bf16(af2, b0, acc[2][0], 0, 0, 0);
            acc[3][0] = __builtin_amdgcn_mfma_f32_16x16x32_bf16(af3, b0, acc[3][0], 0, 0, 0);
            acc[0][1] = __builtin_amdgcn_mfma_f32_16x16x32_bf16(af0, b1, acc[0][1], 0, 0, 0);
            acc[1][1] = __builtin_amdgcn_mfma_f32_16x16x32_bf16(af1, b1, acc[1][1], 0, 0, 0);
            acc[2][1] = __builtin_amdgcn_mfma_f32_16x16x32_bf16(af2, b1, acc[2][1], 0, 0, 0);
            acc[3][1] = __builtin_amdgcn_mfma_f32_16x16x32_bf16(af3, b1, acc[3][1], 0, 0, 0);
            acc[0][2] = __builtin_amdgcn_mfma_f32_16x16x32_bf16(af0, b2, acc[0][2], 0, 0, 0);
            acc[1][2] = __builtin_amdgcn_mfma_f32_16x16x32_bf16(af1, b2, acc[1][2], 0, 0, 0);
            acc[2][2] = __builtin_amdgcn_mfma_f32_16x16x32_bf16(af2, b2, acc[2][2], 0, 0, 0);
            acc[3][2] = __builtin_amdgcn_mfma_f32_16x16x32_bf16(af3, b2, acc[3][2], 0, 0, 0);
            acc[0][3] = __builtin_amdgcn_mfma_f32_16x16x32_bf16(af0, b3, acc[0][3], 0, 0, 0);
            acc[1][3] = __builtin_amdgcn_mfma_f32_16x16x32_bf16(af1, b3, acc[1][3], 0, 0, 0);
            acc[2][3] = __builtin_amdgcn_mfma_f32_16x16x32_bf16(af2, b3, acc[2][3], 0, 0, 0);
            acc[3][3] = __builtin_amdgcn_mfma_f32_16x16x32_bf16(af3, b3, acc[3][3], 0, 0, 0);
            __builtin_amdgcn_s_setprio(0);
            __builtin_amdgcn_s_barrier();

            // ================= phase 1: B nf4-7 (same af), MFMA quadrant nf4-7
            const char* slot1 = smem + LDS_B_OFF + (((t0 + 1) & 3) << 14);
            short8 b4 = *reinterpret_cast<const short8*>(slot1 + bofs);
            short8 b5 = *reinterpret_cast<const short8*>(slot1 + bofs + 1024);
            short8 b6 = *reinterpret_cast<const short8*>(slot1 + bofs + 2048);
            short8 b7 = *reinterpret_cast<const short8*>(slot1 + bofs + 3072);
            ISSUE_HALF(t0 + 4);
            WAITV(t0 + 1);
            __builtin_amdgcn_s_barrier();
            asm volatile("s_waitcnt lgkmcnt(0)" ::: "memory");
            __builtin_amdgcn_sched_barrier(0);
            __builtin_amdgcn_s_setprio(1);
            acc[0][4] = __builtin_amdgcn_mfma_f32_16x16x32_bf16(af0, b4, acc[0][4], 0, 0, 0);
            acc[1][4] = __builtin_amdgcn_mfma_f32_16x16x32_bf16(af1, b4, acc[1][4], 0, 0, 0);
            acc[2][4] = __builtin_amdgcn_mfma_f32_16x16x32_bf16(af2, b4, acc[2][4], 0, 0, 0);
            acc[3][4] = __builtin_amdgcn_mfma_f32_16x16x32_bf16(af3, b4, acc[3][4], 0, 0, 0);
            acc[0][5] = __builtin_amdgcn_mfma_f32_16x16x32_bf16(af0, b5, acc[0][5], 0, 0, 0);
            acc[1][5] = __builtin_amdgcn_mfma_f32_16x16x32_bf16(af1, b5, acc[1][5], 0, 0, 0);
            acc[2][5] = __builtin_amdgcn_mfma_f32_16x16x32_bf16(af2, b5, acc[2][5], 0, 0, 0);
            acc[3][5] = __builtin_amdgcn_mfma_f32_16x16x32_bf16(af3, b5, acc[3][5], 0, 0, 0);
            acc[0][6] = __builtin_amdgcn_mfma_f32_16x16x32_bf16(af0, b6, acc[0][6], 0, 0, 0);
            acc[1][6] = __builtin_amdgcn_mfma_f32_16x16x32_bf16(af1, b6, acc[1][6], 0, 0, 0);
            acc[2][6] = __builtin_amdgcn_mfma_f32_16x16x32_bf16(af2, b6, acc[2][6], 0, 0, 0);
            acc[3][6] = __builtin_amdgcn_mfma_f32_16x16x32_bf16(af3, b6, acc[3][6], 0, 0, 0);
            acc[0][7] = __builtin_amdgcn_mfma_f32_16x16x32_bf16(af0, b7, acc[0][7], 0, 0, 0);
            acc[1][7] = __builtin_amdgcn_mfma_f32_16x16x32_bf16(af1, b7, acc[1][7], 0, 0, 0);
            acc[2][7] = __builtin_amdgcn_mfma_f32_16x16x32_bf16(af2, b7, acc[2][7], 0, 0, 0);
            acc[3][7] = __builtin_amdgcn_mfma_f32_16x16x32_bf16(af3, b7, acc[3][7], 0, 0, 0);
            __builtin_amdgcn_s_setprio(0);
            __builtin_amdgcn_s_barrier();
        }
    }

    // ---- epilogue: bias + relu6 -> shared_act in LDS [128 pos][512 ch] bf16, swizzled
    __syncthreads();
    #pragma unroll
    for (int nf = 0; nf < 8; ++nf) {
        const int ch = wn * 128 + nf * 16 + l15;
        const float bv = bsh[ch];
        #pragma unroll
        for (int mf = 0; mf < 4; ++mf) {
            #pragma unroll
            for (int r = 0; r < 4; ++r) {
                const int pos = wm * 64 + mf * 16 + l4 * 4 + r;
                float v = acc[mf][nf][r] + bv;
                v = fminf(fmaxf(v, 0.f), 6.f);
                *reinterpret_cast<unsigned short*>(
                    smem + pos * 1024 + ((ch * 2) ^ ((pos & 7) << 4))) = f2bf(v);
            }
        }
    }
    __syncthreads();

    // ---- branch GEMM: per wave 16 pos x 96 out, K=512. A=shared_act(LDS), B=wbr(global, L2-hot)
    f32x4 bacc[6];
    #pragma unroll
    for (int nf = 0; nf < 6; ++nf) bacc[nf] = (f32x4){0.f,0.f,0.f,0.f};
    const int pos0 = wid * 16;
    #pragma unroll 4
    for (int kstep = 0; kstep < 16; ++kstep) {
        const int ch = kstep * 32 + l4 * 8;
        const int posr = pos0 + l15;
        short8 af = *reinterpret_cast<const short8*>(
            smem + posr * 1024 + ((ch * 2) ^ ((posr & 7) << 4)));
        #pragma unroll
        for (int nf = 0; nf < 6; ++nf) {
            const int n = nf * 16 + l15;
            short8 bfr = *reinterpret_cast<const short8*>(wbr + n * 512 + ch);
            bacc[nf] = __builtin_amdgcn_mfma_f32_16x16x32_bf16(af, bfr, bacc[nf], 0, 0, 0);
        }
    }

    // ---- branch epilogue: bias, pair-softmax (adjacent n -> shfl_xor 1), scattered f32 stores
    const size_t rowbase = (size_t)h * 128;
    #pragma unroll
    for (int nf = 0; nf < 2; ++nf) {                 // cls: n 0..31 (valid <30)
        const int n = nf * 16 + l15;
        const float bias = (n < 30) ? bcls[n] : 0.f;
        #pragma unroll
        for (int r = 0; r < 4; ++r) {
            float v = bacc[nf][r] + bias;
            float vo = __shfl_xor(v, 1);
            float mx = fmaxf(v, vo);
            float e  = __expf(v - mx), eo = __expf(vo - mx);
            float p  = e / (e + eo);
            if (n < 30) {
                const int wc = pos0 + l4 * 4 + r;
                const size_t anchor = (rowbase + wc) * 15 + (n >> 1);
                const size_t idx = (size_t)bb * 491520 + anchor * 2 + (n & 1);
                out[idx] = v;                        // rpn_class_logits
                out[3932160 + idx] = p;              // rpn_probs
            }
        }
    }
    #pragma unroll
    for (int nf = 2; nf < 6; ++nf) {                 // reg: n 32..95 (valid nr<60)
        const int n = nf * 16 + l15;
        const int nr = n - 32;
        const float bias = (nr < 60) ? breg[nr] : 0.f;
        #pragma unroll
        for (int r = 0; r < 4; ++r) {
            float v = bacc[nf][r] + bias;
            if (nr < 60) {
                const int wc = pos0 + l4 * 4 + r;
                const size_t anchor = (rowbase + wc) * 15 + (nr >> 2);
                out[7864320 + (size_t)bb * 983040 + anchor * 4 + (nr & 3)] = v;  // rpn_deltas
            }
        }
    }
}

extern "C" void kernel_launch(void* const* d_in, const int* in_sizes, int n_in,
                              void* d_out, int out_size, void* d_ws, size_t ws_size,
                              hipStream_t stream) {
    const float* x    = (const float*)d_in[0];
    const float* wsh  = (const float*)d_in[1];
    const float* bsh  = (const float*)d_in[2];
    const float* wcls = (const float*)d_in[3];
    const float* bcls = (const float*)d_in[4];
    const float* wreg = (const float*)d_in[5];
    const float* breg = (const float*)d_in[6];
    float* out = (float*)d_out;

    unsigned short* wk  = (unsigned short*)d_ws;          // 72*512*32 = 1,179,648 bf16 = 2.25 MiB
    unsigned short* wbr = wk + 1179648;                   // 49,152 bf16

    prep_wk <<<288, 256, 0, stream>>>(wsh, wk);
    prep_wbr<<<192, 256, 0, stream>>>(wcls, wreg, wbr);

    hipFuncSetAttribute((const void*)rpn_fused,
                        hipFuncAttributeMaxDynamicSharedMemorySize, LDS_TOTAL);
    rpn_fused<<<1024, 512, LDS_TOTAL, stream>>>(x, wk, bsh, wbr, bcls, breg, out);
}

// Round 5
// 607.716 us; speedup vs baseline: 1.0067x; 1.0067x over previous
//
#include <hip/hip_runtime.h>
#include <stdint.h>

// RPNHead fused: 3x3 conv(256->512,SAME)+relu6 -> {1x1 conv->30 + softmax-pairs, 1x1 conv->60}
// R5: occupancy 2x. Block = M64(row-half) x N512 x K2304, wave tile 64x64 (acc 64 regs),
// A-tile [66][64] cin-quarter (8.4KB), 2x32KB B slots -> 74KB LDS => 2 blocks/CU, 4 waves/SIMD.
// Cross-block wave overlap replaces (failed) intra-block pipelining. Grid 2048.

#define HH 128
#define WW 128
#define CIN 256

typedef __attribute__((ext_vector_type(8))) short short8;
typedef __attribute__((ext_vector_type(4))) float f32x4;

#define SLOT_OFF 8448              // A: [66 pos][64 ch] bf16 swizzled = 8448 B
#define LDS_TOTAL 73984            // + 2 x 32768 B chunk slots (act [64][512]=64KB reuses base)

static __device__ __forceinline__ unsigned short f2bf(float f) {
    uint32_t u = __float_as_uint(f);
    uint32_t r = (u + 0x7FFFu + ((u >> 16) & 1u)) >> 16;
    return (unsigned short)r;
}

// w_shared [3][3][256][512] f32 -> wk [72 chunks][512 n][32 kk] bf16.
// chunk q = q4*18 + dy*6 + dx*2 + kc2 (cin quarter-major, matching consumption order);
// kk pre-swizzled: kk ^ (((n>>1)&3)<<3) (64B rows; both-sides swizzle, linear global_load_lds).
__global__ __launch_bounds__(256) void prep_wk(const float* __restrict__ w,
                                               unsigned short* __restrict__ wk) {
    __shared__ unsigned short t[32][130];
    const int c = blockIdx.x >> 2, nh = blockIdx.x & 3;
    const int dydx = c >> 3, kcg = c & 7;            // kcg = cin/32
    const int dy = dydx / 3, dx = dydx - dy * 3;
    const int q = (kcg >> 1) * 18 + dy * 6 + dx * 2 + (kcg & 1);
    #pragma unroll
    for (int e = 0; e < 16; ++e) {
        int idx = e * 256 + threadIdx.x;              // 32 kk x 128 n
        int kk = idx >> 7, n0 = idx & 127;
        float v = w[((size_t)(dydx * 256 + kcg * 32 + kk)) * 512 + nh * 128 + n0];
        t[kk][n0] = f2bf(v);
    }
    __syncthreads();
    #pragma unroll
    for (int e = 0; e < 16; ++e) {
        int idx = e * 256 + threadIdx.x;              // 128 n x 32 kk
        int n0 = idx >> 5, kk = idx & 31;
        int n = nh * 128 + n0;
        int kks = kk ^ (((n >> 1) & 3) << 3);
        wk[(size_t)q * 16384 + (size_t)n * 32 + kks] = t[kk][n0];
    }
}

// w_cls [512][30], w_reg [512][60] -> wbr [96 n][512 k] bf16 (n 0..29=cls, 32..91=reg, rest 0)
__global__ __launch_bounds__(256) void prep_wbr(const float* __restrict__ wc,
                                                const float* __restrict__ wr,
                                                unsigned short* __restrict__ wbr) {
    int t = blockIdx.x * 256 + threadIdx.x;           // 49,152 total
    int n = t >> 9, k = t & 511;
    float v = 0.f;
    if (n < 30) v = wc[k * 30 + n];
    else if (n >= 32 && n < 92) v = wr[k * 60 + (n - 32)];
    wbr[n * 512 + k] = f2bf(v);
}

__global__ __launch_bounds__(512, 4) void rpn_fused(
    const float* __restrict__ x, const unsigned short* __restrict__ wk,
    const float* __restrict__ bsh, const unsigned short* __restrict__ wbr,
    const float* __restrict__ bcls, const float* __restrict__ breg,
    float* __restrict__ out)
{
    extern __shared__ char smem[];
    const int tid = threadIdx.x;
    const int lane = tid & 63;
    const int wid = tid >> 6;            // 0..7, wave n-band = wid*64
    const int l15 = lane & 15, l4 = lane >> 4;
    const int blk = blockIdx.x;
    const int bb = blk >> 8, h = (blk >> 1) & 127, mh = blk & 1;

    // per-lane constant B byte offset in a slot (nf adds nf*1024); swizzle key (row>>1)&3 = (l15>>1)&3
    const int bofs = (wid * 64 + l15) * 64 + ((l4 * 16) ^ (((l15 >> 1) & 3) << 4));

    f32x4 acc[4][4];                      // [mf][nf], 64 VGPR-equiv
    #pragma unroll
    for (int i = 0; i < 4; ++i)
        #pragma unroll
        for (int j = 0; j < 4; ++j) acc[i][j] = (f32x4){0.f, 0.f, 0.f, 0.f};

#define ISSUE_CHUNK(qq) do {                                                       \
    const char* s_ = reinterpret_cast<const char*>(wk) + ((size_t)(qq) << 15)      \
                     + tid * 16;                                                   \
    char* d_ = smem + SLOT_OFF + (((qq) & 1) << 15) + tid * 16;                    \
    __builtin_amdgcn_global_load_lds(reinterpret_cast<const uint32_t*>(s_),        \
                                     reinterpret_cast<uint32_t*>(d_), 16, 0, 0);   \
    __builtin_amdgcn_global_load_lds(reinterpret_cast<const uint32_t*>(s_ + 8192), \
                                     reinterpret_cast<uint32_t*>(d_ + 8192), 16, 0, 0); \
    __builtin_amdgcn_global_load_lds(reinterpret_cast<const uint32_t*>(s_ + 16384),\
                                     reinterpret_cast<uint32_t*>(d_ + 16384), 16, 0, 0); \
    __builtin_amdgcn_global_load_lds(reinterpret_cast<const uint32_t*>(s_ + 24576),\
                                     reinterpret_cast<uint32_t*>(d_ + 24576), 16, 0, 0); \
} while (0)

    // ---- prologue: stage chunk 0 into slot 0
    ISSUE_CHUNK(0);

    int t = 0;
    for (int q4 = 0; q4 < 4; ++q4) {
        for (int dy = 0; dy < 3; ++dy) {
            // ---- A-stage: [66 pos][64 ch] cin-quarter q4, bf16, swizzled (128 B rows)
            {
                const int hp = h + dy - 1;
                const bool hin = (hp >= 0) && (hp < HH);
                const float* xrow = x + ((size_t)(bb * HH + hp)) * WW * CIN + q4 * 64;
                for (int u = tid; u < 66 * 8; u += 512) {
                    const int pos = u >> 3, c8 = u & 7;
                    const int wc = mh * 64 + pos - 1;
                    float4 f0 = make_float4(0.f,0.f,0.f,0.f), f1 = make_float4(0.f,0.f,0.f,0.f);
                    if (hin && (unsigned)wc < WW) {
                        const float4* p = reinterpret_cast<const float4*>(xrow + (size_t)wc * CIN + c8 * 8);
                        f0 = p[0]; f1 = p[1];
                    }
                    short8 v;
                    v[0]=(short)f2bf(f0.x); v[1]=(short)f2bf(f0.y);
                    v[2]=(short)f2bf(f0.z); v[3]=(short)f2bf(f0.w);
                    v[4]=(short)f2bf(f1.x); v[5]=(short)f2bf(f1.y);
                    v[6]=(short)f2bf(f1.z); v[7]=(short)f2bf(f1.w);
                    *reinterpret_cast<short8*>(smem + pos * 128 + ((c8 * 16) ^ ((pos & 7) << 4))) = v;
                }
            }
            asm volatile("s_waitcnt lgkmcnt(0)" ::: "memory");   // A-writes done (keep vm prefetch alive)
            __builtin_amdgcn_sched_barrier(0);
            __builtin_amdgcn_s_barrier();

            for (int i = 0; i < 6; ++i, ++t) {
                const int dx = i >> 1, kc2 = i & 1;
                // A frags from stable A-tile (overlap the vmcnt/barrier wait)
                const int r0 = l15 + dx;
                const int chh = kc2 * 32 + l4 * 8;
                const int asw = (chh * 2) ^ ((r0 & 7) << 4);
                short8 af0 = *reinterpret_cast<const short8*>(smem + (r0     ) * 128 + asw);
                short8 af1 = *reinterpret_cast<const short8*>(smem + (r0 + 16) * 128 + asw);
                short8 af2 = *reinterpret_cast<const short8*>(smem + (r0 + 32) * 128 + asw);
                short8 af3 = *reinterpret_cast<const short8*>(smem + (r0 + 48) * 128 + asw);
                if (t + 1 < 72) ISSUE_CHUNK(t + 1);              // overwrites slot read at t-1
                if (t < 71) asm volatile("s_waitcnt vmcnt(4)" ::: "memory");
                else        asm volatile("s_waitcnt vmcnt(0)" ::: "memory");
                __builtin_amdgcn_s_barrier();                     // chunk t landed for ALL waves
                const char* slot = smem + SLOT_OFF + ((t & 1) << 15);
                short8 b0 = *reinterpret_cast<const short8*>(slot + bofs);
                short8 b1 = *reinterpret_cast<const short8*>(slot + bofs + 1024);
                short8 b2 = *reinterpret_cast<const short8*>(slot + bofs + 2048);
                short8 b3 = *reinterpret_cast<const short8*>(slot + bofs + 3072);
                asm volatile("s_waitcnt lgkmcnt(0)" ::: "memory");
                __builtin_amdgcn_sched_barrier(0);
                __builtin_amdgcn_s_setprio(1);
                acc[0][0] = __builtin_amdgcn_mfma_f32_16x16x32_bf16(af0, b0, acc[0][0], 0, 0, 0);
                acc[1][0] = __builtin_amdgcn_mfma_f32_16x16x32_bf16(af1, b0, acc[1][0], 0, 0, 0);
                acc[2][0] = __builtin_amdgcn_mfma_f32_16x16x32_bf16(af2, b0, acc[2][0], 0, 0, 0);
                acc[3][0] = __builtin_amdgcn_mfma_f32_16x16x32_bf16(af3, b0, acc[3][0], 0, 0, 0);
                acc[0][1] = __builtin_amdgcn_mfma_f32_16x16x32_bf16(af0, b1, acc[0][1], 0, 0, 0);
                acc[1][1] = __builtin_amdgcn_mfma_f32_16x16x32_bf16(af1, b1, acc[1][1], 0, 0, 0);
                acc[2][1] = __builtin_amdgcn_mfma_f32_16x16x32_bf16(af2, b1, acc[2][1], 0, 0, 0);
                acc[3][1] = __builtin_amdgcn_mfma_f32_16x16x32_bf16(af3, b1, acc[3][1], 0, 0, 0);
                acc[0][2] = __builtin_amdgcn_mfma_f32_16x16x32_bf16(af0, b2, acc[0][2], 0, 0, 0);
                acc[1][2] = __builtin_amdgcn_mfma_f32_16x16x32_bf16(af1, b2, acc[1][2], 0, 0, 0);
                acc[2][2] = __builtin_amdgcn_mfma_f32_16x16x32_bf16(af2, b2, acc[2][2], 0, 0, 0);
                acc[3][2] = __builtin_amdgcn_mfma_f32_16x16x32_bf16(af3, b2, acc[3][2], 0, 0, 0);
                acc[0][3] = __builtin_amdgcn_mfma_f32_16x16x32_bf16(af0, b3, acc[0][3], 0, 0, 0);
                acc[1][3] = __builtin_amdgcn_mfma_f32_16x16x32_bf16(af1, b3, acc[1][3], 0, 0, 0);
                acc[2][3] = __builtin_amdgcn_mfma_f32_16x16x32_bf16(af2, b3, acc[2][3], 0, 0, 0);
                acc[3][3] = __builtin_amdgcn_mfma_f32_16x16x32_bf16(af3, b3, acc[3][3], 0, 0, 0);
                __builtin_amdgcn_s_setprio(0);
                __builtin_amdgcn_s_barrier();                     // all done reading slot (t&1) + A
            }
        }
    }

    // ---- epilogue: bias + relu6 -> act LDS [64 pos][512 ch] bf16 swizzled (reuses A+slots)
    __syncthreads();
    #pragma unroll
    for (int nf = 0; nf < 4; ++nf) {
        const int n = wid * 64 + nf * 16 + l15;
        const float bv = bsh[n];
        #pragma unroll
        for (int mf = 0; mf < 4; ++mf) {
            #pragma unroll
            for (int r = 0; r < 4; ++r) {
                const int pos = mf * 16 + l4 * 4 + r;
                float v = acc[mf][nf][r] + bv;
                v = fminf(fmaxf(v, 0.f), 6.f);
                *reinterpret_cast<unsigned short*>(
                    smem + pos * 1024 + ((n * 2) ^ ((pos & 7) << 4))) = f2bf(v);
            }
        }
    }
    __syncthreads();

    // ---- branch GEMM: wave group (wid>>2) takes 3 nf; each wave 16 pos x 48 out, K=512
    f32x4 bacc[3];
    #pragma unroll
    for (int j = 0; j < 3; ++j) bacc[j] = (f32x4){0.f,0.f,0.f,0.f};
    const int pos0 = (wid & 3) * 16;
    const int nf_off = (wid >> 2) * 3;
    #pragma unroll 4
    for (int kstep = 0; kstep < 16; ++kstep) {
        const int ch = kstep * 32 + l4 * 8;
        const int posr = pos0 + l15;
        short8 af = *reinterpret_cast<const short8*>(
            smem + posr * 1024 + ((ch * 2) ^ ((posr & 7) << 4)));
        #pragma unroll
        for (int j = 0; j < 3; ++j) {
            const int n = (nf_off + j) * 16 + l15;
            short8 bfr = *reinterpret_cast<const short8*>(wbr + n * 512 + ch);
            bacc[j] = __builtin_amdgcn_mfma_f32_16x16x32_bf16(af, bfr, bacc[j], 0, 0, 0);
        }
    }

    // ---- branch epilogue: bias, pair-softmax (adjacent n -> shfl_xor 1), scattered f32 stores
    const size_t rowbase = (size_t)h * 128;
    #pragma unroll
    for (int j = 0; j < 3; ++j) {
        const int nf = nf_off + j;
        const int n = nf * 16 + l15;
        if (nf < 2) {                                 // cls: n 0..31 (valid <30)
            const float bias = (n < 30) ? bcls[n] : 0.f;
            #pragma unroll
            for (int r = 0; r < 4; ++r) {
                float v = bacc[j][r] + bias;
                float vo = __shfl_xor(v, 1);
                float mx = fmaxf(v, vo);
                float e  = __expf(v - mx), eo = __expf(vo - mx);
                float p  = e / (e + eo);
                if (n < 30) {
                    const int wc = mh * 64 + pos0 + l4 * 4 + r;
                    const size_t anchor = (rowbase + wc) * 15 + (n >> 1);
                    const size_t idx = (size_t)bb * 491520 + anchor * 2 + (n & 1);
                    out[idx] = v;                     // rpn_class_logits
                    out[3932160 + idx] = p;           // rpn_probs
                }
            }
        } else {                                      // reg: n 32..95 (valid nr<60)
            const int nr = n - 32;
            const float bias = (nr < 60) ? breg[nr] : 0.f;
            #pragma unroll
            for (int r = 0; r < 4; ++r) {
                float v = bacc[j][r] + bias;
                if (nr < 60) {
                    const int wc = mh * 64 + pos0 + l4 * 4 + r;
                    const size_t anchor = (rowbase + wc) * 15 + (nr >> 2);
                    out[7864320 + (size_t)bb * 983040 + anchor * 4 + (nr & 3)] = v;  // rpn_deltas
                }
            }
        }
    }
}

extern "C" void kernel_launch(void* const* d_in, const int* in_sizes, int n_in,
                              void* d_out, int out_size, void* d_ws, size_t ws_size,
                              hipStream_t stream) {
    const float* x    = (const float*)d_in[0];
    const float* wsh  = (const float*)d_in[1];
    const float* bsh  = (const float*)d_in[2];
    const float* wcls = (const float*)d_in[3];
    const float* bcls = (const float*)d_in[4];
    const float* wreg = (const float*)d_in[5];
    const float* breg = (const float*)d_in[6];
    float* out = (float*)d_out;

    unsigned short* wk  = (unsigned short*)d_ws;          // 72*512*32 = 1,179,648 bf16 = 2.25 MiB
    unsigned short* wbr = wk + 1179648;                   // 49,152 bf16

    prep_wk <<<288, 256, 0, stream>>>(wsh, wk);
    prep_wbr<<<192, 256, 0, stream>>>(wcls, wreg, wbr);

    hipFuncSetAttribute((const void*)rpn_fused,
                        hipFuncAttributeMaxDynamicSharedMemorySize, LDS_TOTAL);
    rpn_fused<<<2048, 512, LDS_TOTAL, stream>>>(x, wk, bsh, wbr, bcls, breg, out);
}